// Round 7
// baseline (102.655 us; speedup 1.0000x reference)
//
#include <hip/hip_runtime.h>
#include <stdint.h>

#define B_  32
#define C_  256
#define HW_ 4096
#define K_  1024

typedef float floatx4 __attribute__((ext_vector_type(4)));

__device__ __forceinline__ uint32_t f2key(float f) {
    uint32_t b = __float_as_uint(f);
    return b ^ ((b & 0x80000000u) ? 0xFFFFFFFFu : 0x80000000u);
}

// K1: fused channel-sum + copy f->out. 512 blocks x 256 threads (8 waves/CU).
// Lane group of 4 owns one float4-pixel; phase j sums channels c==j (mod 4),
// then shfl-combines as (s0+s1)+(s2+s3) -- bit-identical to the verified R4
// summation order (absmax must stay 0). f is loaded NON-TEMPORAL (read exactly
// once in the whole pipeline -> keep it out of L3 so only `out` lives there).
__global__ void __launch_bounds__(256) ps_sumcopy_kernel(const float* __restrict__ f,
                                                         float* __restrict__ out,
                                                         float* __restrict__ sums) {
    int gid   = blockIdx.x * 256 + threadIdx.x;    // 0..131071
    int pix4  = gid >> 2;                          // float4-pixel id 0..32767
    int phase = gid & 3;
    int b     = pix4 >> 10;                        // 1024 float4-pixels per batch
    int p4    = pix4 & 1023;
    const floatx4* base  = (const floatx4*)f + (size_t)b * C_ * (HW_ / 4) + p4;
    floatx4*       obase = (floatx4*)out     + (size_t)b * C_ * (HW_ / 4) + p4;

    float sx = 0.f, sy = 0.f, sz = 0.f, sw = 0.f;
    #pragma unroll 8
    for (int c = phase; c < C_; c += 4) {
        floatx4 v = __builtin_nontemporal_load(base + (size_t)c * (HW_ / 4));
        obase[(size_t)c * (HW_ / 4)] = v;
        sx += v.x; sy += v.y; sz += v.z; sw += v.w;
    }
    // combine phases: r = (s0+s1)+(s2+s3), exact order per component
    float r1x = sx + __shfl_xor(sx, 1);
    float r1y = sy + __shfl_xor(sy, 1);
    float r1z = sz + __shfl_xor(sz, 1);
    float r1w = sw + __shfl_xor(sw, 1);
    float rx = r1x + __shfl_xor(r1x, 2);
    float ry = r1y + __shfl_xor(r1y, 2);
    float rz = r1z + __shfl_xor(r1z, 2);
    float rw = r1w + __shfl_xor(r1w, 2);

    if (phase == 0) {
        floatx4 r = {rx, ry, rz, rw};
        ((floatx4*)sums)[(size_t)b * (HW_ / 4) + p4] = r;
    }
}

// K2: per-batch exact top-K radix select + tie-aware DROPPED-INDEX compaction.
// 32 blocks x 1024 threads. Emits exactly K_=1024 ascending pixel indices per
// batch (the set jax.lax.top_k selects, lowest-index-first tie-break).
__global__ void __launch_bounds__(1024) ps_select_kernel(const float* __restrict__ sums,
                                                         uint32_t* __restrict__ idxlist) {
    __shared__ uint32_t bins[256];
    __shared__ uint32_t wred[16];
    __shared__ uint32_t sh_bcast[2];

    const int b    = blockIdx.x;
    const int t    = threadIdx.x;
    const int lane = t & 63;
    const int wid  = t >> 6;

    float4 v = ((const float4*)(sums + (size_t)b * HW_))[t];
    uint32_t k0 = f2key(v.x), k1 = f2key(v.y), k2 = f2key(v.z), k3 = f2key(v.w);

    uint32_t prefix = 0;
    uint32_t krem   = K_;
    #pragma unroll
    for (int shift = 24; shift >= 0; shift -= 8) {
        if (t < 256) bins[t] = 0;
        __syncthreads();
        uint32_t abovemask = (shift == 24) ? 0u : (0xFFFFFFFFu << (shift + 8));
        if ((k0 & abovemask) == prefix) atomicAdd(&bins[(k0 >> shift) & 255], 1u);
        if ((k1 & abovemask) == prefix) atomicAdd(&bins[(k1 >> shift) & 255], 1u);
        if ((k2 & abovemask) == prefix) atomicAdd(&bins[(k2 >> shift) & 255], 1u);
        if ((k3 & abovemask) == prefix) atomicAdd(&bins[(k3 >> shift) & 255], 1u);
        __syncthreads();
        uint32_t s = 0, binv = 0;
        if (t < 256) {
            int jbin = 255 - t;                    // scan bins from the top
            binv = bins[jbin];
            s = binv;
            #pragma unroll
            for (int off = 1; off < 64; off <<= 1) {
                uint32_t u = __shfl_up(s, off);
                if (lane >= off) s += u;
            }
            if (lane == 63) wred[wid] = s;
        }
        __syncthreads();
        if (t < 256) {
            int jbin = 255 - t;
            uint32_t add = 0;
            for (int w = 0; w < wid; ++w) add += wred[w];
            uint32_t sfx_incl = s + add;           // suffix sum over bins >= jbin
            uint32_t sfx_excl = sfx_incl - binv;   // suffix sum over bins >  jbin
            if (sfx_incl >= krem && sfx_excl < krem) {
                sh_bcast[0] = prefix | ((uint32_t)jbin << shift);
                sh_bcast[1] = krem - sfx_excl;
            }
        }
        __syncthreads();
        prefix = sh_bcast[0];
        krem   = sh_bcast[1];
        __syncthreads();
    }

    const uint32_t T    = prefix;                  // k-th largest key
    const uint32_t need = krem;                    // ties to include, lowest index first

    uint32_t e0 = (k0 == T), e1 = (k1 == T), e2 = (k2 == T), e3 = (k3 == T);
    uint32_t c  = e0 + e1 + e2 + e3;

    // exclusive prefix of tie-count over 1024 threads (thread order == pixel order)
    uint32_t sc = c;
    #pragma unroll
    for (int off = 1; off < 64; off <<= 1) {
        uint32_t u = __shfl_up(sc, off);
        if (lane >= off) sc += u;
    }
    if (lane == 63) wred[wid] = sc;
    __syncthreads();
    uint32_t add = 0;
    for (int w = 0; w < wid; ++w) add += wred[w];
    uint32_t run = (sc - c) + add;                 // ties at lower pixel index

    uint32_t d0 = ((k0 > T) || (e0 && run < need)) ? 1u : 0u; run += e0;
    uint32_t d1 = ((k1 > T) || (e1 && run < need)) ? 1u : 0u; run += e1;
    uint32_t d2 = ((k2 > T) || (e2 && run < need)) ? 1u : 0u; run += e2;
    uint32_t d3 = ((k3 > T) || (e3 && run < need)) ? 1u : 0u; run += e3;
    uint32_t dc = d0 + d1 + d2 + d3;

    // exclusive prefix of drop-count -> compaction offsets (ascending pixel order)
    uint32_t sd = dc;
    #pragma unroll
    for (int off = 1; off < 64; off <<= 1) {
        uint32_t u = __shfl_up(sd, off);
        if (lane >= off) sd += u;
    }
    __syncthreads();                               // protect wred reuse
    if (lane == 63) wred[wid] = sd;
    __syncthreads();
    uint32_t dadd = 0;
    for (int w = 0; w < wid; ++w) dadd += wred[w];
    uint32_t off = (sd - dc) + dadd;               // exclusive prefix over all drops

    uint32_t* dst = idxlist + (size_t)b * K_;
    uint32_t p0 = (uint32_t)t * 4u;
    if (d0) dst[off++] = p0 + 0u;
    if (d1) dst[off++] = p0 + 1u;
    if (d2) dst[off++] = p0 + 2u;
    if (d3) dst[off++] = p0 + 3u;
}

// K3: zero the dropped pixels across channels. 512 blocks x 1024 threads.
// Block = (batch, 16-channel slice); thread t zeroes pixel idxlist[b][t] in
// each of its 16 channels. Indices ascend across lanes -> stores within a wave
// cluster into few cachelines; out is L3-dirty-resident from K1 -> RMW merges.
__global__ void __launch_bounds__(1024) ps_zero_kernel(const uint32_t* __restrict__ idxlist,
                                                       float* __restrict__ out) {
    const int b  = blockIdx.x >> 4;
    const int c0 = (blockIdx.x & 15) << 4;
    uint32_t idx = idxlist[(size_t)b * K_ + threadIdx.x];
    float* obase = out + ((size_t)b * C_ + c0) * HW_ + idx;
    #pragma unroll
    for (int j = 0; j < 16; ++j)
        obase[(size_t)j * HW_] = 0.0f;
}

extern "C" void kernel_launch(void* const* d_in, const int* in_sizes, int n_in,
                              void* d_out, int out_size, void* d_ws, size_t ws_size,
                              hipStream_t stream) {
    const float* f = (const float*)d_in[0];
    float* out = (float*)d_out;

    float*    sums    = (float*)d_ws;                         // 512 KiB
    uint32_t* idxlist = (uint32_t*)(sums + (size_t)B_ * HW_); // 128 KiB

    ps_sumcopy_kernel<<<dim3(512), dim3(256), 0, stream>>>(f, out, sums);
    ps_select_kernel<<<dim3(B_), dim3(1024), 0, stream>>>(sums, idxlist);
    ps_zero_kernel<<<dim3(512), dim3(1024), 0, stream>>>(idxlist, out);
}

// Round 8
// 86.334 us; speedup vs baseline: 1.1891x; 1.1891x over previous
//
#include <hip/hip_runtime.h>
#include <stdint.h>

#define B_  32
#define C_  256
#define HW_ 4096
#define K_  1024

typedef float floatx4 __attribute__((ext_vector_type(4)));

__device__ __forceinline__ uint32_t f2key(float f) {
    uint32_t b = __float_as_uint(f);
    return b ^ ((b & 0x80000000u) ? 0xFFFFFFFFu : 0x80000000u);
}

// Kernel A: per-pixel channel sums, float4 over pixels. 512 blocks x 64 threads;
// each thread owns 4 consecutive pixels. Per-pixel arithmetic order: 4 interleaved
// chains, (s0+s1)+(s2+s3) -- identical to the proven R2 order (mask must not move).
// CHANGE vs R2: unroll 4 -> 8 (32 outstanding loads/lane; at 2 waves/CU the old
// unroll-4 capped in-flight bytes and left sum at ~5 TB/s).
__global__ void ps_sum_kernel(const float4* __restrict__ f4, float4* __restrict__ sums4) {
    int gid = blockIdx.x * 64 + threadIdx.x;       // 0..32767
    int b   = gid >> 10;                           // 1024 float4-pixels per batch
    int p4  = gid & 1023;
    const float4* base = f4 + (size_t)b * C_ * (HW_ / 4) + p4;
    float4 s0 = {0,0,0,0}, s1 = {0,0,0,0}, s2 = {0,0,0,0}, s3 = {0,0,0,0};
    #pragma unroll 8
    for (int c = 0; c < C_; c += 4) {
        float4 v0 = base[(size_t)(c + 0) * (HW_ / 4)];
        float4 v1 = base[(size_t)(c + 1) * (HW_ / 4)];
        float4 v2 = base[(size_t)(c + 2) * (HW_ / 4)];
        float4 v3 = base[(size_t)(c + 3) * (HW_ / 4)];
        s0.x += v0.x; s0.y += v0.y; s0.z += v0.z; s0.w += v0.w;
        s1.x += v1.x; s1.y += v1.y; s1.z += v1.z; s1.w += v1.w;
        s2.x += v2.x; s2.y += v2.y; s2.z += v2.z; s2.w += v2.w;
        s3.x += v3.x; s3.y += v3.y; s3.z += v3.z; s3.w += v3.w;
    }
    float4 r;
    r.x = (s0.x + s1.x) + (s2.x + s3.x);
    r.y = (s0.y + s1.y) + (s2.y + s3.y);
    r.z = (s0.z + s1.z) + (s2.z + s3.z);
    r.w = (s0.w + s1.w) + (s2.w + s3.w);
    sums4[(size_t)b * (HW_ / 4) + p4] = r;
}

// Kernel B: per-batch exact top-K threshold (radix select) + tie-aware mask.
// 32 blocks x 1024 threads. Unchanged (proven exact, ~3 us).
__global__ void __launch_bounds__(1024) ps_select_kernel(const float* __restrict__ sums,
                                                         float* __restrict__ mask) {
    __shared__ uint32_t bins[256];
    __shared__ uint32_t wred[16];
    __shared__ uint32_t sh_bcast[2];

    const int b    = blockIdx.x;
    const int t    = threadIdx.x;
    const int lane = t & 63;
    const int wid  = t >> 6;

    float4 v = ((const float4*)(sums + (size_t)b * HW_))[t];
    uint32_t k0 = f2key(v.x), k1 = f2key(v.y), k2 = f2key(v.z), k3 = f2key(v.w);

    uint32_t prefix = 0;
    uint32_t krem   = K_;
    #pragma unroll
    for (int shift = 24; shift >= 0; shift -= 8) {
        if (t < 256) bins[t] = 0;
        __syncthreads();
        uint32_t abovemask = (shift == 24) ? 0u : (0xFFFFFFFFu << (shift + 8));
        if ((k0 & abovemask) == prefix) atomicAdd(&bins[(k0 >> shift) & 255], 1u);
        if ((k1 & abovemask) == prefix) atomicAdd(&bins[(k1 >> shift) & 255], 1u);
        if ((k2 & abovemask) == prefix) atomicAdd(&bins[(k2 >> shift) & 255], 1u);
        if ((k3 & abovemask) == prefix) atomicAdd(&bins[(k3 >> shift) & 255], 1u);
        __syncthreads();
        uint32_t s = 0, binv = 0;
        if (t < 256) {
            int jbin = 255 - t;                    // scan bins from the top
            binv = bins[jbin];
            s = binv;
            #pragma unroll
            for (int off = 1; off < 64; off <<= 1) {
                uint32_t u = __shfl_up(s, off);
                if (lane >= off) s += u;
            }
            if (lane == 63) wred[wid] = s;
        }
        __syncthreads();
        if (t < 256) {
            int jbin = 255 - t;
            uint32_t add = 0;
            for (int w = 0; w < wid; ++w) add += wred[w];
            uint32_t sfx_incl = s + add;           // suffix sum over bins >= jbin
            uint32_t sfx_excl = sfx_incl - binv;   // suffix sum over bins >  jbin
            if (sfx_incl >= krem && sfx_excl < krem) {
                sh_bcast[0] = prefix | ((uint32_t)jbin << shift);
                sh_bcast[1] = krem - sfx_excl;
            }
        }
        __syncthreads();
        prefix = sh_bcast[0];
        krem   = sh_bcast[1];
        __syncthreads();
    }

    const uint32_t T    = prefix;                  // k-th largest key
    const uint32_t need = krem;                    // ties to include, lowest index first

    uint32_t e0 = (k0 == T), e1 = (k1 == T), e2 = (k2 == T), e3 = (k3 == T);
    uint32_t c  = e0 + e1 + e2 + e3;

    // exclusive prefix over 1024 threads (thread order == pixel order)
    uint32_t sc = c;
    #pragma unroll
    for (int off = 1; off < 64; off <<= 1) {
        uint32_t u = __shfl_up(sc, off);
        if (lane >= off) sc += u;
    }
    if (lane == 63) wred[wid] = sc;
    __syncthreads();
    uint32_t add = 0;
    for (int w = 0; w < wid; ++w) add += wred[w];
    uint32_t run = (sc - c) + add;                 // ties at lower pixel index

    float4 m;
    m.x = ((k0 > T) || (e0 && run < need)) ? 0.0f : 1.0f; run += e0;
    m.y = ((k1 > T) || (e1 && run < need)) ? 0.0f : 1.0f; run += e1;
    m.z = ((k2 > T) || (e2 && run < need)) ? 0.0f : 1.0f; run += e2;
    m.w = ((k3 > T) || (e3 && run < need)) ? 0.0f : 1.0f; run += e3;
    ((float4*)(mask + (size_t)b * HW_))[t] = m;
}

// Kernel C: out = f * mask. 2048 blocks x 256 threads.
// Block = (batch, 16-channel slice, 256-column group). Thread loads its mask
// float4 ONCE, then 16 independent load-mul-NT-store iterations (mask reuse 16x,
// 16 outstanding 16B loads/lane for latency hiding).
__global__ void __launch_bounds__(256) ps_apply_kernel(const float4* __restrict__ f4,
                                                       const float4* __restrict__ mask4,
                                                       float* __restrict__ out) {
    const int bi  = blockIdx.x;
    const int b   = bi >> 6;                       // 64 blocks per batch
    const int cs  = (bi >> 2) & 15;                // 16-channel slice
    const int cg  = bi & 3;                        // column group
    const int c0  = cs << 4;
    const int col = (cg << 8) + threadIdx.x;       // 0..1023 (float4 column)

    float4 m = mask4[((size_t)b << 10) + col];
    const float4* src = f4 + ((size_t)b * C_ + c0) * (HW_ / 4) + col;
    float*        dst = out + ((size_t)b * C_ + c0) * HW_ + (size_t)col * 4;
    #pragma unroll
    for (int j = 0; j < 16; ++j) {
        float4 x = src[(size_t)j * (HW_ / 4)];
        floatx4 r;
        r.x = x.x * m.x; r.y = x.y * m.y; r.z = x.z * m.z; r.w = x.w * m.w;
        __builtin_nontemporal_store(r, (floatx4*)(dst + (size_t)j * HW_));
    }
}

extern "C" void kernel_launch(void* const* d_in, const int* in_sizes, int n_in,
                              void* d_out, int out_size, void* d_ws, size_t ws_size,
                              hipStream_t stream) {
    const float* f = (const float*)d_in[0];
    float* out = (float*)d_out;

    float* sums = (float*)d_ws;                        // 32*4096 floats = 512 KiB
    float* mask = sums + (size_t)B_ * HW_;             // 32*4096 floats = 512 KiB

    ps_sum_kernel<<<dim3(512), dim3(64), 0, stream>>>((const float4*)f, (float4*)sums);
    ps_select_kernel<<<dim3(B_), dim3(1024), 0, stream>>>(sums, mask);
    ps_apply_kernel<<<dim3(2048), dim3(256), 0, stream>>>(
        (const float4*)f, (const float4*)mask, out);
}

// Round 9
// 79.465 us; speedup vs baseline: 1.2918x; 1.0864x over previous
//
#include <hip/hip_runtime.h>
#include <stdint.h>

#define B_  32
#define C_  256
#define HW_ 4096
#define K_  1024

typedef float floatx4 __attribute__((ext_vector_type(4)));

__device__ __forceinline__ uint32_t f2key(float f) {
    uint32_t b = __float_as_uint(f);
    return b ^ ((b & 0x80000000u) ? 0xFFFFFFFFu : 0x80000000u);
}

// Kernel A: per-pixel channel sums. 512 blocks x 256 threads = 8 waves/CU.
// Phase-split x4 (proven bit-exact in R4: chain p sums channels c==p mod 4
// sequentially; combine (s0+s1)+(s2+s3) via shfl). NEW: manual 16-deep load
// blocks so the compiler keeps 16 float4 loads in flight instead of the 4 it
// chose for pragma-unroll (R8: VGPR=36, 800 GB/s, latency-bound).
__global__ void __launch_bounds__(256, 2) ps_sum_kernel(const float4* __restrict__ f4,
                                                        float4* __restrict__ sums4) {
    int gid   = blockIdx.x * 256 + threadIdx.x;    // 0..131071
    int pix4  = gid >> 2;                          // float4-pixel id 0..32767
    int phase = gid & 3;
    int b     = pix4 >> 10;                        // 1024 float4-pixels per batch
    int p4    = pix4 & 1023;
    // chain start: channel = phase; step 4 channels = 4*(HW_/4) float4
    const float4* base = f4 + ((size_t)b * C_ + phase) * (HW_ / 4) + p4;

    float sx = 0.f, sy = 0.f, sz = 0.f, sw = 0.f;
    for (int blk = 0; blk < 4; ++blk) {            // 4 rounds x 16 channels of the chain
        float4 v[16];
        #pragma unroll
        for (int i = 0; i < 16; ++i)
            v[i] = base[(size_t)(blk * 16 + i) * 4 * (HW_ / 4)];
        #pragma unroll
        for (int i = 0; i < 16; ++i) {             // sequential adds, chain order kept
            sx += v[i].x; sy += v[i].y; sz += v[i].z; sw += v[i].w;
        }
    }
    // combine phases: r = (s0+s1)+(s2+s3), exact order per component
    float r1x = sx + __shfl_xor(sx, 1);
    float r1y = sy + __shfl_xor(sy, 1);
    float r1z = sz + __shfl_xor(sz, 1);
    float r1w = sw + __shfl_xor(sw, 1);
    float rx = r1x + __shfl_xor(r1x, 2);
    float ry = r1y + __shfl_xor(r1y, 2);
    float rz = r1z + __shfl_xor(r1z, 2);
    float rw = r1w + __shfl_xor(r1w, 2);

    if (phase == 0) {
        float4 r = {rx, ry, rz, rw};
        ((float4*)sums4)[(size_t)b * (HW_ / 4) + p4] = r;
    }
}

// Kernel B: per-batch exact top-K threshold (radix select) + tie-aware mask.
// 32 blocks x 1024 threads. Unchanged (proven exact, ~3 us).
__global__ void __launch_bounds__(1024) ps_select_kernel(const float* __restrict__ sums,
                                                         float* __restrict__ mask) {
    __shared__ uint32_t bins[256];
    __shared__ uint32_t wred[16];
    __shared__ uint32_t sh_bcast[2];

    const int b    = blockIdx.x;
    const int t    = threadIdx.x;
    const int lane = t & 63;
    const int wid  = t >> 6;

    float4 v = ((const float4*)(sums + (size_t)b * HW_))[t];
    uint32_t k0 = f2key(v.x), k1 = f2key(v.y), k2 = f2key(v.z), k3 = f2key(v.w);

    uint32_t prefix = 0;
    uint32_t krem   = K_;
    #pragma unroll
    for (int shift = 24; shift >= 0; shift -= 8) {
        if (t < 256) bins[t] = 0;
        __syncthreads();
        uint32_t abovemask = (shift == 24) ? 0u : (0xFFFFFFFFu << (shift + 8));
        if ((k0 & abovemask) == prefix) atomicAdd(&bins[(k0 >> shift) & 255], 1u);
        if ((k1 & abovemask) == prefix) atomicAdd(&bins[(k1 >> shift) & 255], 1u);
        if ((k2 & abovemask) == prefix) atomicAdd(&bins[(k2 >> shift) & 255], 1u);
        if ((k3 & abovemask) == prefix) atomicAdd(&bins[(k3 >> shift) & 255], 1u);
        __syncthreads();
        uint32_t s = 0, binv = 0;
        if (t < 256) {
            int jbin = 255 - t;                    // scan bins from the top
            binv = bins[jbin];
            s = binv;
            #pragma unroll
            for (int off = 1; off < 64; off <<= 1) {
                uint32_t u = __shfl_up(s, off);
                if (lane >= off) s += u;
            }
            if (lane == 63) wred[wid] = s;
        }
        __syncthreads();
        if (t < 256) {
            int jbin = 255 - t;
            uint32_t add = 0;
            for (int w = 0; w < wid; ++w) add += wred[w];
            uint32_t sfx_incl = s + add;           // suffix sum over bins >= jbin
            uint32_t sfx_excl = sfx_incl - binv;   // suffix sum over bins >  jbin
            if (sfx_incl >= krem && sfx_excl < krem) {
                sh_bcast[0] = prefix | ((uint32_t)jbin << shift);
                sh_bcast[1] = krem - sfx_excl;
            }
        }
        __syncthreads();
        prefix = sh_bcast[0];
        krem   = sh_bcast[1];
        __syncthreads();
    }

    const uint32_t T    = prefix;                  // k-th largest key
    const uint32_t need = krem;                    // ties to include, lowest index first

    uint32_t e0 = (k0 == T), e1 = (k1 == T), e2 = (k2 == T), e3 = (k3 == T);
    uint32_t c  = e0 + e1 + e2 + e3;

    // exclusive prefix over 1024 threads (thread order == pixel order)
    uint32_t sc = c;
    #pragma unroll
    for (int off = 1; off < 64; off <<= 1) {
        uint32_t u = __shfl_up(sc, off);
        if (lane >= off) sc += u;
    }
    if (lane == 63) wred[wid] = sc;
    __syncthreads();
    uint32_t add = 0;
    for (int w = 0; w < wid; ++w) add += wred[w];
    uint32_t run = (sc - c) + add;                 // ties at lower pixel index

    float4 m;
    m.x = ((k0 > T) || (e0 && run < need)) ? 0.0f : 1.0f; run += e0;
    m.y = ((k1 > T) || (e1 && run < need)) ? 0.0f : 1.0f; run += e1;
    m.z = ((k2 > T) || (e2 && run < need)) ? 0.0f : 1.0f; run += e2;
    m.w = ((k3 > T) || (e3 && run < need)) ? 0.0f : 1.0f; run += e3;
    ((float4*)(mask + (size_t)b * HW_))[t] = m;
}

// Kernel C: out = f * mask. 2048 blocks x 256 threads (32 waves/CU).
// Thread loads its mask float4 ONCE, then 16 independent load-mul-NT-store
// iterations (mask reuse 16x, deep MLP). Unchanged from R8.
__global__ void __launch_bounds__(256) ps_apply_kernel(const float4* __restrict__ f4,
                                                       const float4* __restrict__ mask4,
                                                       float* __restrict__ out) {
    const int bi  = blockIdx.x;
    const int b   = bi >> 6;                       // 64 blocks per batch
    const int cs  = (bi >> 2) & 15;                // 16-channel slice
    const int cg  = bi & 3;                        // column group
    const int c0  = cs << 4;
    const int col = (cg << 8) + threadIdx.x;       // 0..1023 (float4 column)

    float4 m = mask4[((size_t)b << 10) + col];
    const float4* src = f4 + ((size_t)b * C_ + c0) * (HW_ / 4) + col;
    float*        dst = out + ((size_t)b * C_ + c0) * HW_ + (size_t)col * 4;
    #pragma unroll
    for (int j = 0; j < 16; ++j) {
        float4 x = src[(size_t)j * (HW_ / 4)];
        floatx4 r;
        r.x = x.x * m.x; r.y = x.y * m.y; r.z = x.z * m.z; r.w = x.w * m.w;
        __builtin_nontemporal_store(r, (floatx4*)(dst + (size_t)j * HW_));
    }
}

extern "C" void kernel_launch(void* const* d_in, const int* in_sizes, int n_in,
                              void* d_out, int out_size, void* d_ws, size_t ws_size,
                              hipStream_t stream) {
    const float* f = (const float*)d_in[0];
    float* out = (float*)d_out;

    float* sums = (float*)d_ws;                        // 32*4096 floats = 512 KiB
    float* mask = sums + (size_t)B_ * HW_;             // 32*4096 floats = 512 KiB

    ps_sum_kernel<<<dim3(512), dim3(256), 0, stream>>>((const float4*)f, (float4*)sums);
    ps_select_kernel<<<dim3(B_), dim3(1024), 0, stream>>>(sums, mask);
    ps_apply_kernel<<<dim3(2048), dim3(256), 0, stream>>>(
        (const float4*)f, (const float4*)mask, out);
}

// Round 10
// 78.041 us; speedup vs baseline: 1.3154x; 1.0182x over previous
//
#include <hip/hip_runtime.h>
#include <stdint.h>

#define B_  32
#define C_  256
#define HW_ 4096
#define K_  1024

__device__ __forceinline__ uint32_t f2key(float f) {
    uint32_t b = __float_as_uint(f);
    return b ^ ((b & 0x80000000u) ? 0xFFFFFFFFu : 0x80000000u);
}

// Kernel A: per-pixel channel sums. 512 blocks x 256 threads = 8 waves/CU.
// Phase-split x4 (bit-exact per R4/R9: chain p sums channels c==p mod 4
// sequentially; combine (s0+s1)+(s2+s3) via shfl). Manual 16-deep load blocks
// keep 16 float4 loads in flight (R8's pragma unroll was refused: VGPR=36,
// 800 GB/s latency-bound; this version cut ~7 us in the R9 A/B).
__global__ void __launch_bounds__(256, 2) ps_sum_kernel(const float4* __restrict__ f4,
                                                        float4* __restrict__ sums4) {
    int gid   = blockIdx.x * 256 + threadIdx.x;    // 0..131071
    int pix4  = gid >> 2;                          // float4-pixel id 0..32767
    int phase = gid & 3;
    int b     = pix4 >> 10;                        // 1024 float4-pixels per batch
    int p4    = pix4 & 1023;
    const float4* base = f4 + ((size_t)b * C_ + phase) * (HW_ / 4) + p4;

    float sx = 0.f, sy = 0.f, sz = 0.f, sw = 0.f;
    for (int blk = 0; blk < 4; ++blk) {            // 4 rounds x 16 channels of the chain
        float4 v[16];
        #pragma unroll
        for (int i = 0; i < 16; ++i)
            v[i] = base[(size_t)(blk * 16 + i) * 4 * (HW_ / 4)];
        #pragma unroll
        for (int i = 0; i < 16; ++i) {             // sequential adds, chain order kept
            sx += v[i].x; sy += v[i].y; sz += v[i].z; sw += v[i].w;
        }
    }
    float r1x = sx + __shfl_xor(sx, 1);
    float r1y = sy + __shfl_xor(sy, 1);
    float r1z = sz + __shfl_xor(sz, 1);
    float r1w = sw + __shfl_xor(sw, 1);
    float rx = r1x + __shfl_xor(r1x, 2);
    float ry = r1y + __shfl_xor(r1y, 2);
    float rz = r1z + __shfl_xor(r1z, 2);
    float rw = r1w + __shfl_xor(r1w, 2);

    if (phase == 0) {
        float4 r = {rx, ry, rz, rw};
        sums4[(size_t)b * (HW_ / 4) + p4] = r;
    }
}

// Kernel B: per-batch exact top-K threshold (radix select) + tie-aware mask.
// 32 blocks x 1024 threads. Unchanged (proven exact, ~3 us).
__global__ void __launch_bounds__(1024) ps_select_kernel(const float* __restrict__ sums,
                                                         float* __restrict__ mask) {
    __shared__ uint32_t bins[256];
    __shared__ uint32_t wred[16];
    __shared__ uint32_t sh_bcast[2];

    const int b    = blockIdx.x;
    const int t    = threadIdx.x;
    const int lane = t & 63;
    const int wid  = t >> 6;

    float4 v = ((const float4*)(sums + (size_t)b * HW_))[t];
    uint32_t k0 = f2key(v.x), k1 = f2key(v.y), k2 = f2key(v.z), k3 = f2key(v.w);

    uint32_t prefix = 0;
    uint32_t krem   = K_;
    #pragma unroll
    for (int shift = 24; shift >= 0; shift -= 8) {
        if (t < 256) bins[t] = 0;
        __syncthreads();
        uint32_t abovemask = (shift == 24) ? 0u : (0xFFFFFFFFu << (shift + 8));
        if ((k0 & abovemask) == prefix) atomicAdd(&bins[(k0 >> shift) & 255], 1u);
        if ((k1 & abovemask) == prefix) atomicAdd(&bins[(k1 >> shift) & 255], 1u);
        if ((k2 & abovemask) == prefix) atomicAdd(&bins[(k2 >> shift) & 255], 1u);
        if ((k3 & abovemask) == prefix) atomicAdd(&bins[(k3 >> shift) & 255], 1u);
        __syncthreads();
        uint32_t s = 0, binv = 0;
        if (t < 256) {
            int jbin = 255 - t;                    // scan bins from the top
            binv = bins[jbin];
            s = binv;
            #pragma unroll
            for (int off = 1; off < 64; off <<= 1) {
                uint32_t u = __shfl_up(s, off);
                if (lane >= off) s += u;
            }
            if (lane == 63) wred[wid] = s;
        }
        __syncthreads();
        if (t < 256) {
            int jbin = 255 - t;
            uint32_t add = 0;
            for (int w = 0; w < wid; ++w) add += wred[w];
            uint32_t sfx_incl = s + add;           // suffix sum over bins >= jbin
            uint32_t sfx_excl = sfx_incl - binv;   // suffix sum over bins >  jbin
            if (sfx_incl >= krem && sfx_excl < krem) {
                sh_bcast[0] = prefix | ((uint32_t)jbin << shift);
                sh_bcast[1] = krem - sfx_excl;
            }
        }
        __syncthreads();
        prefix = sh_bcast[0];
        krem   = sh_bcast[1];
        __syncthreads();
    }

    const uint32_t T    = prefix;                  // k-th largest key
    const uint32_t need = krem;                    // ties to include, lowest index first

    uint32_t e0 = (k0 == T), e1 = (k1 == T), e2 = (k2 == T), e3 = (k3 == T);
    uint32_t c  = e0 + e1 + e2 + e3;

    // exclusive prefix over 1024 threads (thread order == pixel order)
    uint32_t sc = c;
    #pragma unroll
    for (int off = 1; off < 64; off <<= 1) {
        uint32_t u = __shfl_up(sc, off);
        if (lane >= off) sc += u;
    }
    if (lane == 63) wred[wid] = sc;
    __syncthreads();
    uint32_t add = 0;
    for (int w = 0; w < wid; ++w) add += wred[w];
    uint32_t run = (sc - c) + add;                 // ties at lower pixel index

    float4 m;
    m.x = ((k0 > T) || (e0 && run < need)) ? 0.0f : 1.0f; run += e0;
    m.y = ((k1 > T) || (e1 && run < need)) ? 0.0f : 1.0f; run += e1;
    m.z = ((k2 > T) || (e2 && run < need)) ? 0.0f : 1.0f; run += e2;
    m.w = ((k3 > T) || (e3 && run < need)) ? 0.0f : 1.0f; run += e3;
    ((float4*)(mask + (size_t)b * HW_))[t] = m;
}

// Kernel C: out = f * mask — EXACT R2 version (the 76.2-us best): linear walk,
// per-element mask load (L2-resident), plain float4 store. R8's channel-sliced
// register-mask variant regressed ~10 us (16 distant write streams per block).
__global__ void ps_apply_kernel(const float4* __restrict__ f4,
                                const float4* __restrict__ mask4,
                                float4* __restrict__ out4) {
    size_t i = (size_t)blockIdx.x * blockDim.x + threadIdx.x;  // over 8388608 float4s
    float4 v = f4[i];
    size_t b  = i >> 18;           // (C_*HW_/4) = 262144 float4 per batch
    size_t p4 = i & 1023;          // HW_/4 - 1
    float4 m = mask4[(b << 10) + p4];
    v.x *= m.x; v.y *= m.y; v.z *= m.z; v.w *= m.w;
    out4[i] = v;
}

extern "C" void kernel_launch(void* const* d_in, const int* in_sizes, int n_in,
                              void* d_out, int out_size, void* d_ws, size_t ws_size,
                              hipStream_t stream) {
    const float* f = (const float*)d_in[0];
    float* out = (float*)d_out;

    float* sums = (float*)d_ws;                        // 32*4096 floats = 512 KiB
    float* mask = sums + (size_t)B_ * HW_;             // 32*4096 floats = 512 KiB

    ps_sum_kernel<<<dim3(512), dim3(256), 0, stream>>>((const float4*)f, (float4*)sums);
    ps_select_kernel<<<dim3(B_), dim3(1024), 0, stream>>>(sums, mask);

    size_t total4 = (size_t)B_ * C_ * HW_ / 4;         // 8388608
    ps_apply_kernel<<<dim3((unsigned)(total4 / 256)), dim3(256), 0, stream>>>(
        (const float4*)f, (const float4*)mask, (float4*)out);
}